// Round 6
// baseline (195.611 us; speedup 1.0000x reference)
//
#include <hip/hip_runtime.h>

#define MB   2048   // model batches
#define NP   8192   // num points (scan length)
#define NF   8      // number of functions
#define RM   51     // removed leading iterations
#define NCH  64     // chunks per batch
#define CH   128    // NP / NCH, steps per chunk

typedef float        f32x4 __attribute__((ext_vector_type(4)));
typedef unsigned int u32;

// ws layout (bytes): mapsA float4[NCH*MB] @0 (2MB) | mapsC float2[NCH*MB] @2MB (1MB)
//                    pe float2[NCH*MB] @3MB (1MB)  | bar int[2] @4MB (memset/launch)

__global__ __launch_bounds__(256, 2) void ifs_fused(
    const float2* __restrict__ point, const float* __restrict__ W,
    const float* __restrict__ B, const float* __restrict__ OPS,
    const int* __restrict__ idxg,
    float4* __restrict__ mapsA, float2* __restrict__ mapsC,
    float2* __restrict__ pe, int* __restrict__ bar,
    float* __restrict__ out)
{
    // stride 35: step-loop reads addr=tid*35+j -> bank (3*tid+j)%32, 2-way = free
    __shared__ u32 ptile[256][35];                 // 128 packed codes / row (35.8 KB)
    __shared__ __align__(16) float4 tA[NF];        // {w00,w01,w10,w11} conflict-free b128
    __shared__ __align__(16) float4 tB[NF];        // {b0,b1,op,0}
    __shared__ __align__(16) float sbuf[4][256][3];// transpose buffer (12 KB)

    const int tid = threadIdx.x;
    const int bid = blockIdx.x;
    const int c   = bid >> 3;
    const int b0  = (bid & 7) << 8;
    const int b   = b0 + tid;

    if (tid < NF) {
        tA[tid] = make_float4(W[tid*4+0], W[tid*4+1], W[tid*4+2], W[tid*4+3]);
        tB[tid] = make_float4(B[tid*2+0], B[tid*2+1], OPS[tid], 0.f);
    }
    const int x8 = tid & 7, yy = tid >> 3;

    // ---------------- Phase A: stage (packed) + compose, overlapped ----------------
    auto stage = [&](int seg) {
        #pragma unroll
        for (int p = 0; p < 8; ++p) {
            const int row = yy + p * 32;           // 8 lanes x int4 = 128B/row, 16 lines/instr
            const int4 v = *(const int4*)(idxg + (size_t)(b0 + row) * NP
                                          + c * CH + seg * 32 + x8 * 4);
            ptile[row][seg * 8 + x8] =
                (u32)v.x | ((u32)v.y << 8) | ((u32)v.z << 16) | ((u32)v.w << 24);
        }
    };
    stage(0);
    __syncthreads();

    float a00 = 1.f, a01 = 0.f, a10 = 0.f, a11 = 1.f, c0 = 0.f, c1 = 0.f;
    for (int seg = 0; seg < 4; ++seg) {
        if (seg < 3) stage(seg + 1);               // overlap fetch with compose
        #pragma unroll
        for (int j = 0; j < 8; ++j) {
            const u32 pc = ptile[tid][seg * 8 + j];
            #pragma unroll
            for (int e = 0; e < 4; ++e) {
                const int f = (pc >> (8 * e)) & 7;
                const float4 wl = tA[f];
                const float4 wh = tB[f];
                const float na00 = wl.x*a00 + wl.y*a10;
                const float na01 = wl.x*a01 + wl.y*a11;
                const float na10 = wl.z*a00 + wl.w*a10;
                const float na11 = wl.z*a01 + wl.w*a11;
                const float nc0  = wl.x*c0  + wl.y*c1 + wh.x;
                const float nc1  = wl.z*c0  + wl.w*c1 + wh.y;
                a00 = na00; a01 = na01; a10 = na10; a11 = na11; c0 = nc0; c1 = nc1;
            }
        }
        __syncthreads();                            // publish next seg's staging
    }
    mapsA[(size_t)c * MB + b] = make_float4(a00, a01, a10, a11);
    mapsC[(size_t)c * MB + b] = make_float2(c0, c1);

    // ---------------- Barrier 1: all 512 blocks arrived ----------------
    __threadfence();
    __syncthreads();
    if (tid == 0)
        __hip_atomic_fetch_add(&bar[0], 1, __ATOMIC_ACQ_REL, __HIP_MEMORY_SCOPE_AGENT);

    // ---------------- Phase B: designated scan (blocks c==0) ----------------
    if (c == 0) {
        if (tid == 0)
            while (__hip_atomic_load(&bar[0], __ATOMIC_ACQUIRE, __HIP_MEMORY_SCOPE_AGENT) < 512)
                __builtin_amdgcn_s_sleep(2);
        __syncthreads();

        float2 p = point[b];
        float4 A0[8]; float2 C0[8]; float4 A1[8]; float2 C1[8];
        #pragma unroll
        for (int k = 0; k < 8; ++k) {
            A0[k] = mapsA[(size_t)k * MB + b];
            C0[k] = mapsC[(size_t)k * MB + b];
        }
        for (int g = 0; g < 8; ++g) {
            if (g < 7) {
                #pragma unroll
                for (int k = 0; k < 8; ++k) {
                    A1[k] = mapsA[(size_t)((g + 1) * 8 + k) * MB + b];
                    C1[k] = mapsC[(size_t)((g + 1) * 8 + k) * MB + b];
                }
            }
            #pragma unroll
            for (int k = 0; k < 8; ++k) {
                pe[(size_t)(g * 8 + k) * MB + b] = p;     // entry state of chunk
                const float nx = A0[k].x * p.x + A0[k].y * p.y + C0[k].x;
                const float ny = A0[k].z * p.x + A0[k].w * p.y + C0[k].y;
                p.x = nx; p.y = ny;
            }
            #pragma unroll
            for (int k = 0; k < 8; ++k) { A0[k] = A1[k]; C0[k] = C1[k]; }
        }
        __threadfence();
        __syncthreads();
        if (tid == 0)
            __hip_atomic_fetch_add(&bar[1], 1, __ATOMIC_ACQ_REL, __HIP_MEMORY_SCOPE_AGENT);
    }

    // ---------------- Barrier 2: pe ready ----------------
    if (tid == 0)
        while (__hip_atomic_load(&bar[1], __ATOMIC_ACQUIRE, __HIP_MEMORY_SCOPE_AGENT) < 8)
            __builtin_amdgcn_s_sleep(2);
    __syncthreads();

    // ---------------- Phase C: replay from LDS codes, transpose-coalesced out ----------------
    float2 p = pe[(size_t)c * MB + b];
    int s_[3], r_[3];
    #pragma unroll
    for (int k = 0; k < 3; ++k) {
        const int w = 4 * (tid + 256 * k);          // flat word in 4x256x3 group tile
        s_[k] = w / 768;
        r_[k] = w - s_[k] * 768;
    }
    long long off[3];
    #pragma unroll
    for (int k = 0; k < 3; ++k)
        off[k] = (long long)(c * CH + s_[k] - RM) * (MB * 3) + b0 * 3 + r_[k];

    const bool chk = (c == 0);
    for (int grp = 0; grp < 32; ++grp) {            // 4 steps per group
        const u32 pc = ptile[tid][grp];
        #pragma unroll
        for (int s = 0; s < 4; ++s) {
            const int f = (pc >> (8 * s)) & 7;
            const float4 wl = tA[f];
            const float4 wh = tB[f];
            const float nx = wl.x * p.x + wl.y * p.y + wh.x;
            const float ny = wl.z * p.x + wl.w * p.y + wh.y;
            p.x = nx; p.y = ny;
            sbuf[s][tid][0] = p.x;                  // stride-3 b32: 2-way = free
            sbuf[s][tid][1] = p.y;
            sbuf[s][tid][2] = wh.z;
        }
        __syncthreads();
        const int t0 = grp * 4;
        const float* flat = &sbuf[0][0][0];
        #pragma unroll
        for (int k = 0; k < 3; ++k) {
            if (!chk || (t0 + s_[k]) >= RM) {
                const f32x4 v = *(const f32x4*)(flat + 4 * (tid + 256 * k));
                __builtin_nontemporal_store(v, (f32x4*)(out + off[k]));
            }
            off[k] += 4LL * (MB * 3);
        }
        __syncthreads();
    }
}

extern "C" void kernel_launch(void* const* d_in, const int* in_sizes, int n_in,
                              void* d_out, int out_size, void* d_ws, size_t ws_size,
                              hipStream_t stream) {
    const float* point = (const float*)d_in[0];  // [2048,2,1]
    const float* W     = (const float*)d_in[1];  // [8,2,2]
    const float* B     = (const float*)d_in[2];  // [8,2,1]
    const float* OPS   = (const float*)d_in[3];  // [8]
    const int*   idx   = (const int*)  d_in[4];  // [2048,8192]
    float*       out   = (float*)d_out;          // [(8192-51)*2048, 3]

    char* ws = (char*)d_ws;
    float4* mapsA = (float4*)(ws);                                   // 2 MB
    float2* mapsC = (float2*)(ws + (size_t)NCH * MB * 16);           // 1 MB
    float2* pe    = (float2*)(ws + (size_t)NCH * MB * 24);           // 1 MB
    int*    bar   = (int*)   (ws + (size_t)NCH * MB * 32);           // 128 B

    hipMemsetAsync(bar, 0, 128, stream);         // reset spin-barrier counters (graph-safe)
    ifs_fused<<<NCH * (MB / 256), 256, 0, stream>>>(
        (const float2*)point, W, B, OPS, idx, mapsA, mapsC, pe, bar, out);
}

// Round 7
// 72.910 us; speedup vs baseline: 2.6829x; 2.6829x over previous
//
#include <hip/hip_runtime.h>
#include <hip/hip_fp16.h>

#define MB   2048   // model batches
#define NP   8192   // num points (scan length)
#define NF   8      // number of functions
#define RM   51     // removed leading iterations
#define NCH  64     // chunks per batch
#define CH   128    // NP / NCH, steps per chunk

typedef float        f32x4 __attribute__((ext_vector_type(4)));
typedef unsigned int u32;

// ws layout: mapsA float4[NCH*MB] @0 (2MB) | mapsC float2[NCH*MB] @2MB (1MB)
//            pe float2[NCH*MB] @3MB (1MB)

// f16 table: one uint4 per function = {h2(w00,w01), h2(w10,w11), h2(b0,b1), h2(op,0)}
// 8 entries x 16B -> b128 reads hit 8 distinct bank-quads: conflict-free.
__device__ __forceinline__ void build_tbl(u32 (*tbl)[4], const float* W,
                                          const float* B, const float* OPS, int tid)
{
    if (tid < NF) {
        const __half2 h0 = __floats2half2_rn(W[tid*4+0], W[tid*4+1]);
        const __half2 h1 = __floats2half2_rn(W[tid*4+2], W[tid*4+3]);
        const __half2 h2 = __floats2half2_rn(B[tid*2+0], B[tid*2+1]);
        const __half2 h3 = __floats2half2_rn(OPS ? OPS[tid] : 0.f, 0.f);
        tbl[tid][0] = __builtin_bit_cast(u32, h0);
        tbl[tid][1] = __builtin_bit_cast(u32, h1);
        tbl[tid][2] = __builtin_bit_cast(u32, h2);
        tbl[tid][3] = __builtin_bit_cast(u32, h3);
    }
}

// ---------------- Phase 1: per-chunk affine composition ----------------
__global__ __launch_bounds__(256, 4) void ifs_phase1(
    const int* __restrict__ idxg, const float* __restrict__ W,
    const float* __restrict__ B,
    float4* __restrict__ mapsA, float2* __restrict__ mapsC)
{
    __shared__ u32 ptile[256][33];              // packed codes: 32 words = 128 steps
    __shared__ __align__(16) u32 tbl[NF][4];
    const int tid = threadIdx.x;
    build_tbl(tbl, W, B, nullptr, tid);

    const int c  = blockIdx.x >> 3;
    const int b0 = (blockIdx.x & 7) << 8;
    const int x8 = tid & 7, yy = tid >> 3;

    auto stage = [&](int seg) {
        #pragma unroll
        for (int p = 0; p < 8; ++p) {
            const int row = yy + p * 32;        // 8 lanes x int4 = 128B/row: coalesced
            const int4 v = *(const int4*)(idxg + (size_t)(b0 + row) * NP
                                          + c * CH + seg * 32 + x8 * 4);
            ptile[row][seg * 8 + x8] =
                (u32)v.x | ((u32)v.y << 8) | ((u32)v.z << 16) | ((u32)v.w << 24);
        }
    };
    stage(0);
    __syncthreads();

    float a00 = 1.f, a01 = 0.f, a10 = 0.f, a11 = 1.f, c0 = 0.f, c1 = 0.f;
    for (int seg = 0; seg < 4; ++seg) {
        if (seg < 3) stage(seg + 1);            // overlap fetch with compose
        #pragma unroll
        for (int j = 0; j < 8; ++j) {
            const u32 pc = ptile[tid][seg * 8 + j];
            #pragma unroll
            for (int e = 0; e < 4; ++e) {
                const int f = (pc >> (8 * e)) & 7;
                const uint4 u = *(const uint4*)&tbl[f][0];   // ONE b128 per step
                const float2 w0 = __half22float2(__builtin_bit_cast(__half2, u.x));
                const float2 w1 = __half22float2(__builtin_bit_cast(__half2, u.y));
                const float2 bb = __half22float2(__builtin_bit_cast(__half2, u.z));
                const float na00 = w0.x*a00 + w0.y*a10;
                const float na01 = w0.x*a01 + w0.y*a11;
                const float na10 = w1.x*a00 + w1.y*a10;
                const float na11 = w1.x*a01 + w1.y*a11;
                const float nc0  = w0.x*c0  + w0.y*c1 + bb.x;
                const float nc1  = w1.x*c0  + w1.y*c1 + bb.y;
                a00 = na00; a01 = na01; a10 = na10; a11 = na11; c0 = nc0; c1 = nc1;
            }
        }
        __syncthreads();
    }
    mapsA[(size_t)c * MB + b0 + tid] = make_float4(a00, a01, a10, a11);
    mapsC[(size_t)c * MB + b0 + tid] = make_float2(c0, c1);
}

// ---------------- Phase 2: sequential scan over chunk maps (8-deep prefetch) ----------------
__global__ __launch_bounds__(64) void ifs_phase2(
    const float2* __restrict__ point, const float4* __restrict__ mapsA,
    const float2* __restrict__ mapsC, float2* __restrict__ pe)
{
    const int b = blockIdx.x * 64 + threadIdx.x;   // 32 blocks -> 32 CUs
    float2 p = point[b];
    float4 A0[8], A1[8]; float2 C0[8], C1[8];
    #pragma unroll
    for (int k = 0; k < 8; ++k) {
        A0[k] = mapsA[(size_t)k * MB + b];
        C0[k] = mapsC[(size_t)k * MB + b];
    }
    for (int g = 0; g < 8; ++g) {
        if (g < 7) {
            #pragma unroll
            for (int k = 0; k < 8; ++k) {
                A1[k] = mapsA[(size_t)((g + 1) * 8 + k) * MB + b];
                C1[k] = mapsC[(size_t)((g + 1) * 8 + k) * MB + b];
            }
        }
        #pragma unroll
        for (int k = 0; k < 8; ++k) {
            pe[(size_t)(g * 8 + k) * MB + b] = p;
            const float nx = A0[k].x * p.x + A0[k].y * p.y + C0[k].x;
            const float ny = A0[k].z * p.x + A0[k].w * p.y + C0[k].y;
            p.x = nx; p.y = ny;
        }
        #pragma unroll
        for (int k = 0; k < 8; ++k) { A0[k] = A1[k]; C0[k] = C1[k]; }
    }
}

// ---------------- Phase 3: replay chunks, transpose-coalesced output ----------------
__global__ __launch_bounds__(256, 2) void ifs_phase3(
    const int* __restrict__ idxg, const float* __restrict__ W,
    const float* __restrict__ B, const float* __restrict__ OPS,
    const float2* __restrict__ pe, float* __restrict__ out)
{
    __shared__ u32 ptile[256][33];                       // packed codes (33.8 KB)
    __shared__ __align__(16) float sbuf[2][4][256][4];   // padded ping-pong (32 KB)
    __shared__ __align__(16) u32 tbl[NF][4];
    const int tid = threadIdx.x;
    build_tbl(tbl, W, B, OPS, tid);

    const int c  = blockIdx.x >> 3;
    const int b0 = (blockIdx.x & 7) << 8;
    const int x8 = tid & 7, yy = tid >> 3;

    auto stage = [&](int seg) {
        #pragma unroll
        for (int p = 0; p < 8; ++p) {
            const int row = yy + p * 32;
            const int4 v = *(const int4*)(idxg + (size_t)(b0 + row) * NP
                                          + c * CH + seg * 32 + x8 * 4);
            ptile[row][seg * 8 + x8] =
                (u32)v.x | ((u32)v.y << 8) | ((u32)v.z << 16) | ((u32)v.w << 24);
        }
    };
    stage(0);

    float2 p = pe[(size_t)c * MB + b0 + tid];

    // store-side decomposition: f32x4 k covers output words w=4*(tid+256k) of the
    // 4x256x3-word group tile; step s=w/768, col r=w%768
    int s_[3], r_[3];
    #pragma unroll
    for (int k = 0; k < 3; ++k) {
        const int w = 4 * (tid + 256 * k);
        s_[k] = w / 768;
        r_[k] = w - s_[k] * 768;
    }
    long long off[3];
    #pragma unroll
    for (int k = 0; k < 3; ++k)
        off[k] = (long long)(c * CH + s_[k] - RM) * (MB * 3) + b0 * 3 + r_[k];

    const bool chk = (c == 0);
    __syncthreads();                                      // stage(0) + tbl visible

    for (int span = 0; span < 4; ++span) {                // 4 x 32 steps
        if (span < 3) stage(span + 1);                    // overlap fetch with compute
        #pragma unroll
        for (int g = 0; g < 8; ++g) {                     // group = 4 steps
            const int buf = g & 1;
            const u32 pc = ptile[tid][span * 8 + g];
            #pragma unroll
            for (int s = 0; s < 4; ++s) {
                const int f = (pc >> (8 * s)) & 7;
                const uint4 u = *(const uint4*)&tbl[f][0];        // ONE b128
                const float2 w0 = __half22float2(__builtin_bit_cast(__half2, u.x));
                const float2 w1 = __half22float2(__builtin_bit_cast(__half2, u.y));
                const float2 bb = __half22float2(__builtin_bit_cast(__half2, u.z));
                const float op  = __low2float(__builtin_bit_cast(__half2, u.w));
                const float nx = w0.x * p.x + w0.y * p.y + bb.x;
                const float ny = w1.x * p.x + w1.y * p.y + bb.y;
                p.x = nx; p.y = ny;
                f32x4 o4 = {nx, ny, op, 0.f};
                *(f32x4*)&sbuf[buf][s][tid][0] = o4;              // ONE b128 write
            }
            __syncthreads();
            const int t0 = span * 32 + g * 4;
            const float* flat = &sbuf[buf][0][0][0];
            #pragma unroll
            for (int k = 0; k < 3; ++k) {
                if (!chk || (t0 + s_[k]) >= RM) {
                    const int w = 4 * (tid + 256 * k) - 768 * s_[k];  // word in step-row
                    const int b1 = w / 3, cm0 = w - b1 * 3;
                    // gather 4 consecutive output words from padded row
                    const float* row = flat + s_[k] * 1024;
                    f32x4 v;
                    int bb_ = b1, cc_ = cm0;
                    #pragma unroll
                    for (int j = 0; j < 4; ++j) {
                        v[j] = row[bb_ * 4 + cc_];
                        if (++cc_ == 3) { cc_ = 0; ++bb_; }
                    }
                    __builtin_nontemporal_store(v, (f32x4*)(out + off[k]));
                }
                off[k] += 4LL * (MB * 3);
            }
        }
    }
}

extern "C" void kernel_launch(void* const* d_in, const int* in_sizes, int n_in,
                              void* d_out, int out_size, void* d_ws, size_t ws_size,
                              hipStream_t stream) {
    const float* point = (const float*)d_in[0];  // [2048,2,1]
    const float* W     = (const float*)d_in[1];  // [8,2,2]
    const float* B     = (const float*)d_in[2];  // [8,2,1]
    const float* OPS   = (const float*)d_in[3];  // [8]
    const int*   idx   = (const int*)  d_in[4];  // [2048,8192]
    float*       out   = (float*)d_out;          // [(8192-51)*2048, 3]

    char* ws = (char*)d_ws;
    float4* mapsA = (float4*)(ws);                                 // 2 MB
    float2* mapsC = (float2*)(ws + (size_t)NCH * MB * 16);         // 1 MB
    float2* pe    = (float2*)(ws + (size_t)NCH * MB * 24);         // 1 MB

    ifs_phase1<<<NCH * (MB / 256), 256, 0, stream>>>(idx, W, B, mapsA, mapsC);
    ifs_phase2<<<MB / 64, 64, 0, stream>>>((const float2*)point, mapsA, mapsC, pe);
    ifs_phase3<<<NCH * (MB / 256), 256, 0, stream>>>(idx, W, B, OPS, pe, out);
}